// Round 1
// baseline (411.268 us; speedup 1.0000x reference)
//
#include <hip/hip_runtime.h>

// OrthogonalAddTSU: sequential scan over S steps, carry h:(B,H).
// Per step: cos = <h,s>/max(|h||s|,eps); h = clip(h + (s - h*cos)*m, -1, 1).
// B=64, H=1024, S=512. One wave (64 lanes) per batch; 16 h-elements per lane.
// Reduction is a pure in-register DPP butterfly: no LDS, no barriers.

#define NB 64
#define NH 1024
#define NS 512
#define EL 16  // h elements per lane (64 * 16 = 1024 = H)

template <int CTRL>
__device__ __forceinline__ float dpp_add(float x) {
  // x + dpp_shifted(x); bound_ctrl=1 -> out-of-bounds lanes contribute 0
  int s = __builtin_amdgcn_update_dpp(0, __builtin_bit_cast(int, x), CTRL, 0xf,
                                      0xf, true);
  return x + __builtin_bit_cast(float, s);
}

// Full wave64 sum, result broadcast via readlane(63) -> SGPR (lane-uniform).
__device__ __forceinline__ float wave_sum64(float x) {
  x = dpp_add<0x111>(x);  // row_shr:1
  x = dpp_add<0x112>(x);  // row_shr:2
  x = dpp_add<0x114>(x);  // row_shr:4
  x = dpp_add<0x118>(x);  // row_shr:8  -> lane 15 of each row16 = row sum
  x = dpp_add<0x142>(x);  // row_bcast:15 -> lane31=sum(0..31), lane63=sum(32..63)
  x = dpp_add<0x143>(x);  // row_bcast:31 -> lane63 = total
  return __builtin_bit_cast(
      float, __builtin_amdgcn_readlane(__builtin_bit_cast(int, x), 63));
}

__device__ __forceinline__ float readlane_f(float v, int lane) {
  return __builtin_bit_cast(
      float, __builtin_amdgcn_readlane(__builtin_bit_cast(int, v), lane));
}

__global__ __launch_bounds__(64, 1) void otsu_scan_kernel(
    const float* __restrict__ tree,   // (B,H)
    const float* __restrict__ seq,    // (B,H,S)
    const float* __restrict__ mask,   // (B,S)
    float* __restrict__ out) {        // (B,H)
  const int b = blockIdx.x;
  const int lane = threadIdx.x;  // 0..63

  // --- load initial h: 16 contiguous elements per lane ---
  const float* hrow = tree + b * NH + lane * EL;
  float h[EL];
#pragma unroll
  for (int i = 0; i < EL / 4; ++i) {
    float4 v = *(const float4*)(hrow + 4 * i);
    h[4 * i + 0] = v.x;
    h[4 * i + 1] = v.y;
    h[4 * i + 2] = v.z;
    h[4 * i + 3] = v.w;
  }

  // seq row base for this lane's 16 h-indices; element i, group g at
  // srow + i*NS + 4*g  (each lane streams 16 contiguous-in-t rows)
  const float* srow = seq + (size_t)b * NH * NS + (size_t)(lane * EL) * NS;

  float4 bufA[EL], bufB[EL];

  auto prefetch = [&](float4* buf, int g) {
#pragma unroll
    for (int i = 0; i < EL; ++i)
      buf[i] = *(const float4*)(srow + i * NS + 4 * g);
  };

  float mvec = 0.0f;  // masks for current 64-step supergroup, one per lane

  // Process the 4 steps of one group. lbase = (t & 63) of step j=0.
  auto process = [&](const float4* buf, int lbase, bool has_t0) {
#pragma unroll
    for (int j = 0; j < 4; ++j) {
      const float m = readlane_f(mvec, lbase + j);  // wave-uniform
      // m==0 && t>0: h provably unchanged (already clipped) -> skip step.
      // t==0 must still apply clip even when m==0.
      if (m != 0.0f || (has_t0 && j == 0)) {
        float d[4] = {0.f, 0.f, 0.f, 0.f};
        float e[4] = {0.f, 0.f, 0.f, 0.f};
        float f[4] = {0.f, 0.f, 0.f, 0.f};
#pragma unroll
        for (int i = 0; i < EL; ++i) {
          const float sv = ((const float*)&buf[i])[j];
          d[i & 3] = fmaf(h[i], sv, d[i & 3]);     // dot partial
          e[i & 3] = fmaf(h[i], h[i], e[i & 3]);   // |h|^2 partial
          f[i & 3] = fmaf(sv, sv, f[i & 3]);       // |s|^2 partial
        }
        float dot = (d[0] + d[1]) + (d[2] + d[3]);
        float h2 = (e[0] + e[1]) + (e[2] + e[3]);
        float s2 = (f[0] + f[1]) + (f[2] + f[3]);
        dot = wave_sum64(dot);
        h2 = wave_sum64(h2);
        s2 = wave_sum64(s2);
        const float denom = fmaxf(sqrtf(h2 * s2), 1e-8f);
        const float c = dot / denom;
        const float a = 1.0f - c * m;  // h_new = h*(1 - cos*m) + s*m, clipped
#pragma unroll
        for (int i = 0; i < EL; ++i) {
          const float sv = ((const float*)&buf[i])[j];
          const float u = fmaf(sv, m, h[i] * a);
          h[i] = fminf(fmaxf(u, -1.0f), 1.0f);
        }
      }
    }
  };

  prefetch(bufA, 0);

  // 8 supergroups x 64 steps; 16 float4-groups per supergroup, unrolled x2
  for (int sg = 0; sg < NS / 64; ++sg) {
    mvec = mask[b * NS + sg * 64 + lane];
    for (int gg = 0; gg < 16; gg += 2) {
      const int g = sg * 16 + gg;
      prefetch(bufB, g + 1);
      process(bufA, 4 * gg, g == 0);
      if (g + 2 < NS / 4) prefetch(bufA, g + 2);
      process(bufB, 4 * gg + 4, false);
    }
  }

  // --- write final h ---
  float* orow = out + b * NH + lane * EL;
#pragma unroll
  for (int i = 0; i < EL / 4; ++i) {
    float4 v;
    v.x = h[4 * i + 0];
    v.y = h[4 * i + 1];
    v.z = h[4 * i + 2];
    v.w = h[4 * i + 3];
    *(float4*)(orow + 4 * i) = v;
  }
}

extern "C" void kernel_launch(void* const* d_in, const int* in_sizes, int n_in,
                              void* d_out, int out_size, void* d_ws,
                              size_t ws_size, hipStream_t stream) {
  const float* tree = (const float*)d_in[0];  // (64,1024)
  const float* seq = (const float*)d_in[1];   // (64,1024,512)
  const float* mask = (const float*)d_in[2];  // (64,512)
  float* out = (float*)d_out;                 // (64,1024)
  otsu_scan_kernel<<<dim3(NB), dim3(64), 0, stream>>>(tree, seq, mask, out);
}

// Round 2
// 321.196 us; speedup vs baseline: 1.2804x; 1.2804x over previous
//
#include <hip/hip_runtime.h>

// OrthogonalAddTSU: sequential scan over S steps, carry h:(B,H).
// Per step: cos = <h,s>/max(|h||s|,eps); h = clip(h + (s - h*cos)*m, -1, 1).
// B=64, H=1024, S=512. One wave (64 lanes) per batch; 16 h-elements per lane.
// Reduction is in-register DPP butterfly: no LDS, no barriers.
// Key facts exploited:
//  - mask is exactly binary (0.0/1.0): m==0 steps are skipped entirely
//    (h already clipped => unchanged), m==1 steps drop the *m multiplies.
//  - rcp/med3/sqrt approximations are fine vs 2e-2 absmax threshold.
//  - sched_barrier(0) after each prefetch pins the register double buffer
//    (round 1: compiler sank loads to use, VGPR=84, latency fully exposed).

#define NB 64
#define NH 1024
#define NS 512
#define EL 16  // h elements per lane (64 * 16 = 1024 = H)

template <int CTRL>
__device__ __forceinline__ float dpp_add(float x) {
  // x + dpp_shifted(x); bound_ctrl=1 -> out-of-bounds lanes contribute 0
  int s = __builtin_amdgcn_update_dpp(0, __builtin_bit_cast(int, x), CTRL, 0xf,
                                      0xf, true);
  return x + __builtin_bit_cast(float, s);
}

__device__ __forceinline__ float readlane_f(float v, int lane) {
  return __builtin_bit_cast(
      float, __builtin_amdgcn_readlane(__builtin_bit_cast(int, v), lane));
}

// Three wave64 sums with interleaved butterfly stages (3 independent chains).
__device__ __forceinline__ void wave_sum3(float& a, float& b, float& c) {
  a = dpp_add<0x111>(a); b = dpp_add<0x111>(b); c = dpp_add<0x111>(c);
  a = dpp_add<0x112>(a); b = dpp_add<0x112>(b); c = dpp_add<0x112>(c);
  a = dpp_add<0x114>(a); b = dpp_add<0x114>(b); c = dpp_add<0x114>(c);
  a = dpp_add<0x118>(a); b = dpp_add<0x118>(b); c = dpp_add<0x118>(c);
  a = dpp_add<0x142>(a); b = dpp_add<0x142>(b); c = dpp_add<0x142>(c);
  a = dpp_add<0x143>(a); b = dpp_add<0x143>(b); c = dpp_add<0x143>(c);
  a = readlane_f(a, 63);
  b = readlane_f(b, 63);
  c = readlane_f(c, 63);
}

__global__ __launch_bounds__(64, 1) void otsu_scan_kernel(
    const float* __restrict__ tree,   // (B,H)
    const float* __restrict__ seq,    // (B,H,S)
    const float* __restrict__ mask,   // (B,S)
    float* __restrict__ out) {        // (B,H)
  const int b = blockIdx.x;
  const int lane = threadIdx.x;  // 0..63

  // --- load initial h: 16 contiguous elements per lane ---
  const float* hrow = tree + b * NH + lane * EL;
  float h[EL];
#pragma unroll
  for (int i = 0; i < EL / 4; ++i) {
    float4 v = *(const float4*)(hrow + 4 * i);
    h[4 * i + 0] = v.x;
    h[4 * i + 1] = v.y;
    h[4 * i + 2] = v.z;
    h[4 * i + 3] = v.w;
  }

  // --- preload ALL mask words for this batch: 8 supergroups x 64 lanes ---
  float m8[8];
#pragma unroll
  for (int k = 0; k < 8; ++k) m8[k] = mask[b * NS + k * 64 + lane];

  // seq row base for this lane's 16 h-indices; element i, group g at
  // srow + i*NS + 4*g  (each lane streams 16 contiguous-in-t rows)
  const float* srow = seq + (size_t)b * NH * NS + (size_t)(lane * EL) * NS;

  float bufA[4 * EL], bufB[4 * EL];

  auto prefetch = [&](float* buf, int g) {
    const float* p = srow + 4 * g;
#pragma unroll
    for (int i = 0; i < EL; ++i) {
      float4 v = *(const float4*)(p + i * NS);
      buf[4 * i + 0] = v.x;
      buf[4 * i + 1] = v.y;
      buf[4 * i + 2] = v.z;
      buf[4 * i + 3] = v.w;
    }
    // Pin: nothing schedules across -> loads issue HERE, results stay in
    // registers through the following process() (true double buffer).
    __builtin_amdgcn_sched_barrier(0);
  };

  // One full step with m==1 (mask is binary; m==0 steps are skipped).
  auto full_step = [&](const float* buf, int j) {
    float d0 = 0.f, d1 = 0.f, d2 = 0.f, d3 = 0.f;  // dot partials
    float e0 = 0.f, e1 = 0.f, e2 = 0.f, e3 = 0.f;  // |h|^2 partials
    float f0 = 0.f, f1 = 0.f, f2 = 0.f, f3 = 0.f;  // |s|^2 partials
#pragma unroll
    for (int i = 0; i < EL; i += 4) {
      const float s0 = buf[4 * (i + 0) + j];
      const float s1 = buf[4 * (i + 1) + j];
      const float s2v = buf[4 * (i + 2) + j];
      const float s3 = buf[4 * (i + 3) + j];
      d0 = fmaf(h[i + 0], s0, d0);
      d1 = fmaf(h[i + 1], s1, d1);
      d2 = fmaf(h[i + 2], s2v, d2);
      d3 = fmaf(h[i + 3], s3, d3);
      e0 = fmaf(h[i + 0], h[i + 0], e0);
      e1 = fmaf(h[i + 1], h[i + 1], e1);
      e2 = fmaf(h[i + 2], h[i + 2], e2);
      e3 = fmaf(h[i + 3], h[i + 3], e3);
      f0 = fmaf(s0, s0, f0);
      f1 = fmaf(s1, s1, f1);
      f2 = fmaf(s2v, s2v, f2);
      f3 = fmaf(s3, s3, f3);
    }
    float dot = (d0 + d1) + (d2 + d3);
    float h2 = (e0 + e1) + (e2 + e3);
    float s2 = (f0 + f1) + (f2 + f3);
    wave_sum3(dot, h2, s2);
    const float denom = fmaxf(__builtin_amdgcn_sqrtf(h2 * s2), 1e-8f);
    const float c = dot * __builtin_amdgcn_rcpf(denom);  // |c|<=1
    const float a = 1.0f - c;  // m==1: h_new = clip(h*(1-c) + s)
#pragma unroll
    for (int i = 0; i < EL; ++i) {
      h[i] = __builtin_amdgcn_fmed3f(fmaf(h[i], a, buf[4 * i + j]), -1.0f,
                                     1.0f);
    }
  };

  // Process the 4 steps of one group. lbase = (t & 63) of step j=0.
  auto process = [&](const float* buf, float mvec, int lbase, bool has_t0) {
#pragma unroll
    for (int j = 0; j < 4; ++j) {
      const float m = readlane_f(mvec, lbase + j);  // wave-uniform (SGPR)
      if (m != 0.0f) {
        full_step(buf, j);
      } else if (has_t0 && j == 0) {
        // t==0, m==0: h_new = clip(h) (clip applies even to masked step 0)
#pragma unroll
        for (int i = 0; i < EL; ++i)
          h[i] = __builtin_amdgcn_fmed3f(h[i], -1.0f, 1.0f);
      }
      // m==0, t>0: h already clipped -> provably unchanged, skip.
    }
  };

  prefetch(bufA, 0);

  // 8 supergroups x 64 steps; 16 float4-groups per supergroup, ping-pong x2.
  // Outer loop unrolled so m8[sg] stays a register (no dynamic indexing).
#pragma unroll
  for (int sg = 0; sg < 8; ++sg) {
    const float mvec = m8[sg];
    for (int gg = 0; gg < 16; gg += 2) {
      const int g = sg * 16 + gg;
      prefetch(bufB, g + 1);
      process(bufA, mvec, 4 * gg, sg == 0 && gg == 0);
      if (g + 2 < NS / 4) prefetch(bufA, g + 2);
      process(bufB, mvec, 4 * gg + 4, false);
    }
  }

  // --- write final h ---
  float* orow = out + b * NH + lane * EL;
#pragma unroll
  for (int i = 0; i < EL / 4; ++i) {
    float4 v;
    v.x = h[4 * i + 0];
    v.y = h[4 * i + 1];
    v.z = h[4 * i + 2];
    v.w = h[4 * i + 3];
    *(float4*)(orow + 4 * i) = v;
  }
}

extern "C" void kernel_launch(void* const* d_in, const int* in_sizes, int n_in,
                              void* d_out, int out_size, void* d_ws,
                              size_t ws_size, hipStream_t stream) {
  const float* tree = (const float*)d_in[0];  // (64,1024)
  const float* seq = (const float*)d_in[1];   // (64,1024,512)
  const float* mask = (const float*)d_in[2];  // (64,512)
  float* out = (float*)d_out;                 // (64,1024)
  otsu_scan_kernel<<<dim3(NB), dim3(64), 0, stream>>>(tree, seq, mask, out);
}

// Round 4
// 314.121 us; speedup vs baseline: 1.3093x; 1.0225x over previous
//
#include <hip/hip_runtime.h>

// OrthogonalAddTSU: sequential scan over S steps, carry h:(B,H).
// Per step: cos = <h,s>/max(|h||s|,eps); h = clip(h + (s - h*cos)*m, -1, 1).
// B=64, H=1024, S=512. One wave per batch; 16 h-elements per lane.
//
// Round-4 structure (round-3 + offset fix):
//  - ALL global loads via volatile inline asm. The seq stream is a ping-pong
//    register double buffer (2 x 16 x dwordx4) gated by asm s_waitcnt
//    vmcnt(16) with operand-tied buffers. sched_barrier failed in round 2
//    (IR sinking ignores it, VGPR=100 showed one buffer); asm cannot be sunk.
//    Issue-ahead ping-pong gives ~2 group-times of latency distance.
//  - global_* imm offset is 13-bit SIGNED (-4096..4095): row pointers are
//    biased +4096 B so 4 rows sit at offsets -4096,-2048,0,+2048.
//  - No compiler-tracked VMEM loads in the kernel, so compiler vmcnt
//    bookkeeping can't misfire over our asm loads.
//  - |s|^2 batched per 4-step group: 4 interleaved DPP chains.
//  - cos = dot * rsq(max(h2*s2, 1e-16)) : one transcendental on the chain.
//  - mask binary: m==0 steps skipped (h already clipped => unchanged; t==0
//    still needs the clip).

#define NB 64
#define NH 1024
#define NS 512
#define EL 16

typedef float v4f __attribute__((ext_vector_type(4)));

template <int CTRL>
__device__ __forceinline__ float dpp_add(float x) {
  int s = __builtin_amdgcn_update_dpp(0, __builtin_bit_cast(int, x), CTRL, 0xf,
                                      0xf, true);
  return x + __builtin_bit_cast(float, s);
}

__device__ __forceinline__ float readlane_f(float v, int lane) {
  return __builtin_bit_cast(
      float, __builtin_amdgcn_readlane(__builtin_bit_cast(int, v), lane));
}

__device__ __forceinline__ void wave_sum2(float& a, float& b) {
  a = dpp_add<0x111>(a); b = dpp_add<0x111>(b);
  a = dpp_add<0x112>(a); b = dpp_add<0x112>(b);
  a = dpp_add<0x114>(a); b = dpp_add<0x114>(b);
  a = dpp_add<0x118>(a); b = dpp_add<0x118>(b);
  a = dpp_add<0x142>(a); b = dpp_add<0x142>(b);
  a = dpp_add<0x143>(a); b = dpp_add<0x143>(b);
  a = readlane_f(a, 63);
  b = readlane_f(b, 63);
}

__device__ __forceinline__ void wave_sum4(float& a, float& b, float& c,
                                          float& d) {
  a = dpp_add<0x111>(a); b = dpp_add<0x111>(b); c = dpp_add<0x111>(c); d = dpp_add<0x111>(d);
  a = dpp_add<0x112>(a); b = dpp_add<0x112>(b); c = dpp_add<0x112>(c); d = dpp_add<0x112>(d);
  a = dpp_add<0x114>(a); b = dpp_add<0x114>(b); c = dpp_add<0x114>(c); d = dpp_add<0x114>(d);
  a = dpp_add<0x118>(a); b = dpp_add<0x118>(b); c = dpp_add<0x118>(c); d = dpp_add<0x118>(d);
  a = dpp_add<0x142>(a); b = dpp_add<0x142>(b); c = dpp_add<0x142>(c); d = dpp_add<0x142>(d);
  a = dpp_add<0x143>(a); b = dpp_add<0x143>(b); c = dpp_add<0x143>(c); d = dpp_add<0x143>(d);
  a = readlane_f(a, 63);
  b = readlane_f(b, 63);
  c = readlane_f(c, 63);
  d = readlane_f(d, 63);
}

// volatile asm loads: cannot be sunk/reordered vs other volatile asm.
#define GLD4(dst, p, OFFSTR)                                   \
  asm volatile("global_load_dwordx4 %0, %1, off" OFFSTR        \
               : "=v"(dst)                                     \
               : "v"(p))
#define GLD1(dst, p)                                           \
  asm volatile("global_load_dword %0, %1, off" : "=v"(dst) : "v"(p))

// Issue one group (16 rows x 16B) and advance the 4 row-base pointers.
// Pointers are biased +4096 B: rows at offsets -4096,-2048,0,+2048.
#define ISSUE16(buf)                       \
  do {                                     \
    GLD4(buf[0], p0, " offset:-4096");     \
    GLD4(buf[1], p0, " offset:-2048");     \
    GLD4(buf[2], p0, "");                  \
    GLD4(buf[3], p0, " offset:2048");      \
    GLD4(buf[4], p1, " offset:-4096");     \
    GLD4(buf[5], p1, " offset:-2048");     \
    GLD4(buf[6], p1, "");                  \
    GLD4(buf[7], p1, " offset:2048");      \
    GLD4(buf[8], p2, " offset:-4096");     \
    GLD4(buf[9], p2, " offset:-2048");     \
    GLD4(buf[10], p2, "");                 \
    GLD4(buf[11], p2, " offset:2048");     \
    GLD4(buf[12], p3, " offset:-4096");    \
    GLD4(buf[13], p3, " offset:-2048");    \
    GLD4(buf[14], p3, "");                 \
    GLD4(buf[15], p3, " offset:2048");     \
    p0 += 4; p1 += 4; p2 += 4; p3 += 4;    \
  } while (0)

// Wait until <=N VMEM loads outstanding; tie buffer regs so every later use
// is data-dependent on the wait. (vmcnt decrements in issue order -> leaving
// the N newest outstanding guarantees this buffer's 16 are done.)
#define WAITPIN(buf, N)                                             \
  do {                                                              \
    asm volatile("s_waitcnt vmcnt(" N ")"                           \
                 : "+v"(buf[0]), "+v"(buf[1]), "+v"(buf[2]),        \
                   "+v"(buf[3]), "+v"(buf[4]), "+v"(buf[5]),        \
                   "+v"(buf[6]), "+v"(buf[7]));                     \
    asm volatile("s_waitcnt vmcnt(" N ")"                           \
                 : "+v"(buf[8]), "+v"(buf[9]), "+v"(buf[10]),       \
                   "+v"(buf[11]), "+v"(buf[12]), "+v"(buf[13]),     \
                   "+v"(buf[14]), "+v"(buf[15]));                   \
  } while (0)

__global__ __launch_bounds__(64, 1) void otsu_scan_kernel(
    const float* __restrict__ tree,   // (B,H)
    const float* __restrict__ seq,    // (B,H,S)
    const float* __restrict__ mask,   // (B,S)
    float* __restrict__ out) {        // (B,H)
  const int b = blockIdx.x;
  const int lane = threadIdx.x;  // 0..63

  // --- h and masks: also via asm loads + one full drain, so the compiler
  //     never tracks any VMEM load of its own in this kernel. ---
  const float* hrow = tree + b * NH + lane * EL;
  v4f hv[4];
  GLD4(hv[0], hrow, "");
  GLD4(hv[1], hrow, " offset:16");
  GLD4(hv[2], hrow, " offset:32");
  GLD4(hv[3], hrow, " offset:48");
  float m8[8];
  {
    const float* mp = mask + b * NS + lane;
    GLD1(m8[0], mp);
    GLD1(m8[1], mp + 64);
    GLD1(m8[2], mp + 128);
    GLD1(m8[3], mp + 192);
    GLD1(m8[4], mp + 256);
    GLD1(m8[5], mp + 320);
    GLD1(m8[6], mp + 384);
    GLD1(m8[7], mp + 448);
  }
  asm volatile("s_waitcnt vmcnt(0)"
               : "+v"(hv[0]), "+v"(hv[1]), "+v"(hv[2]), "+v"(hv[3]),
                 "+v"(m8[0]), "+v"(m8[1]), "+v"(m8[2]), "+v"(m8[3]),
                 "+v"(m8[4]), "+v"(m8[5]), "+v"(m8[6]), "+v"(m8[7]));

  float h[EL];
#pragma unroll
  for (int k = 0; k < 4; ++k) {
    h[4 * k + 0] = hv[k].x;
    h[4 * k + 1] = hv[k].y;
    h[4 * k + 2] = hv[k].z;
    h[4 * k + 3] = hv[k].w;
  }

  // seq row-base pointers for this lane, biased +1024 floats (4096 B):
  // p0 serves rows 0..3, p1 rows 4..7, p2 rows 8..11, p3 rows 12..15.
  const float* srow = seq + (size_t)b * NH * NS + (size_t)(lane * EL) * NS;
  const float* p0 = srow + 2 * NS;
  const float* p1 = srow + 6 * NS;
  const float* p2 = srow + 10 * NS;
  const float* p3 = srow + 14 * NS;

  v4f bufA[16], bufB[16];

  // Process one 4-step group. lbase = (t & 63) of the group's first step.
  auto process4 = [&](const v4f* buf, float mv, int lbase, bool has_t0) {
    // batched |s|^2 for the 4 steps: 64 FMA + 4 interleaved DPP chains
    float fA0 = 0.f, fA1 = 0.f, fA2 = 0.f, fA3 = 0.f;
    float fB0 = 0.f, fB1 = 0.f, fB2 = 0.f, fB3 = 0.f;
#pragma unroll
    for (int i = 0; i < EL; i += 2) {
      fA0 = fmaf(buf[i][0], buf[i][0], fA0);
      fA1 = fmaf(buf[i][1], buf[i][1], fA1);
      fA2 = fmaf(buf[i][2], buf[i][2], fA2);
      fA3 = fmaf(buf[i][3], buf[i][3], fA3);
      fB0 = fmaf(buf[i + 1][0], buf[i + 1][0], fB0);
      fB1 = fmaf(buf[i + 1][1], buf[i + 1][1], fB1);
      fB2 = fmaf(buf[i + 1][2], buf[i + 1][2], fB2);
      fB3 = fmaf(buf[i + 1][3], buf[i + 1][3], fB3);
    }
    float s2g[4];
    s2g[0] = fA0 + fB0;
    s2g[1] = fA1 + fB1;
    s2g[2] = fA2 + fB2;
    s2g[3] = fA3 + fB3;
    wave_sum4(s2g[0], s2g[1], s2g[2], s2g[3]);

#pragma unroll
    for (int j = 0; j < 4; ++j) {
      const float m = readlane_f(mv, lbase + j);  // wave-uniform
      if (m != 0.0f) {
        float d0 = 0.f, d1 = 0.f, d2 = 0.f, d3 = 0.f;
        float e0 = 0.f, e1 = 0.f, e2 = 0.f, e3 = 0.f;
#pragma unroll
        for (int i = 0; i < EL; i += 4) {
          const float sA = buf[i + 0][j];
          const float sB = buf[i + 1][j];
          const float sC = buf[i + 2][j];
          const float sD = buf[i + 3][j];
          d0 = fmaf(h[i + 0], sA, d0);
          e0 = fmaf(h[i + 0], h[i + 0], e0);
          d1 = fmaf(h[i + 1], sB, d1);
          e1 = fmaf(h[i + 1], h[i + 1], e1);
          d2 = fmaf(h[i + 2], sC, d2);
          e2 = fmaf(h[i + 2], h[i + 2], e2);
          d3 = fmaf(h[i + 3], sD, d3);
          e3 = fmaf(h[i + 3], h[i + 3], e3);
        }
        float dot = (d0 + d1) + (d2 + d3);
        float hh = (e0 + e1) + (e2 + e3);
        wave_sum2(dot, hh);
        const float p = fmaxf(hh * s2g[j], 1e-16f);  // denom^2, eps=1e-8
        const float c = dot * __builtin_amdgcn_rsqf(p);
        const float a = 1.0f - c;  // m==1: h_new = clip(h*(1-c) + s)
#pragma unroll
        for (int i = 0; i < EL; ++i)
          h[i] = __builtin_amdgcn_fmed3f(fmaf(h[i], a, buf[i][j]), -1.0f,
                                         1.0f);
      } else if (has_t0 && j == 0) {
        // t==0, m==0: clip still applies
#pragma unroll
        for (int i = 0; i < EL; ++i)
          h[i] = __builtin_amdgcn_fmed3f(h[i], -1.0f, 1.0f);
      }
      // m==0, t>0: h already clipped -> unchanged, skip.
    }
  };

  ISSUE16(bufA);  // group 0

  // 8 supergroups (64 steps each). sg<7: 8 iters x 2 groups; sg==7: 7 iters
  // + explicit 2-group tail (avoids issuing OOB group 128).
#pragma unroll
  for (int sg = 0; sg < 8; ++sg) {
    const float mv = m8[sg];
    const int nIter = (sg == 7) ? 7 : 8;
    for (int it = 0; it < nIter; ++it) {
      const int lbase = 8 * it;  // step-in-supergroup of this iter's 8 steps
      ISSUE16(bufB);             // group g+1
      WAITPIN(bufA, "16");       // g's 16 done (<=16 left = newest = B's)
      process4(bufA, mv, lbase, sg == 0 && it == 0);
      ISSUE16(bufA);             // group g+2
      WAITPIN(bufB, "16");
      process4(bufB, mv, lbase + 4, false);
    }
  }
  {  // tail: groups 126 (A) and 127 (B) = steps 504..511
    const float mv = m8[7];
    ISSUE16(bufB);  // group 127 (last issue; pointers end exactly at row end)
    WAITPIN(bufA, "16");
    process4(bufA, mv, 56, false);
    WAITPIN(bufB, "0");
    process4(bufB, mv, 60, false);
  }

  // --- write final h ---
  float* orow = out + b * NH + lane * EL;
#pragma unroll
  for (int i = 0; i < EL / 4; ++i) {
    float4 v;
    v.x = h[4 * i + 0];
    v.y = h[4 * i + 1];
    v.z = h[4 * i + 2];
    v.w = h[4 * i + 3];
    *(float4*)(orow + 4 * i) = v;
  }
}

extern "C" void kernel_launch(void* const* d_in, const int* in_sizes, int n_in,
                              void* d_out, int out_size, void* d_ws,
                              size_t ws_size, hipStream_t stream) {
  const float* tree = (const float*)d_in[0];  // (64,1024)
  const float* seq = (const float*)d_in[1];   // (64,1024,512)
  const float* mask = (const float*)d_in[2];  // (64,512)
  float* out = (float*)d_out;                 // (64,1024)
  otsu_scan_kernel<<<dim3(NB), dim3(64), 0, stream>>>(tree, seq, mask, out);
}